// Round 1
// baseline (425.600 us; speedup 1.0000x reference)
//
#include <hip/hip_runtime.h>
#include <math.h>

// ---------------------------------------------------------------------------
// AdaRound fake-quantize with global outlier mask.
//  Phase 1: partial (sum, sumsq) of X -> ws (double2[RED_BLOCKS])
//  Phase 2: fold partials -> float2{mu, 3*sd} at ws + RED_BLOCKS
//  Phase 3: elementwise fake quant + outlier passthrough
// ---------------------------------------------------------------------------

constexpr int RED_BLOCKS  = 2048;
constexpr int RED_THREADS = 256;

__global__ __launch_bounds__(RED_THREADS)
void stats_partial_kernel(const float4* __restrict__ x4,
                          double2* __restrict__ part, int n4) {
    double s = 0.0, ss = 0.0;
    const int stride = gridDim.x * blockDim.x;
    for (int i = blockIdx.x * blockDim.x + threadIdx.x; i < n4; i += stride) {
        float4 v = x4[i];
        double vx = v.x, vy = v.y, vz = v.z, vw = v.w;
        s  += (vx + vy) + (vz + vw);
        ss += (vx * vx + vy * vy) + (vz * vz + vw * vw);
    }
    // wave64 butterfly
    for (int off = 32; off > 0; off >>= 1) {
        s  += __shfl_down(s,  off, 64);
        ss += __shfl_down(ss, off, 64);
    }
    __shared__ double sh[8];  // 4 waves * {s, ss}
    const int wave = threadIdx.x >> 6;
    if ((threadIdx.x & 63) == 0) { sh[wave * 2] = s; sh[wave * 2 + 1] = ss; }
    __syncthreads();
    if (threadIdx.x == 0) {
        double ts = 0.0, tss = 0.0;
        for (int w = 0; w < (RED_THREADS >> 6); ++w) {
            ts += sh[w * 2]; tss += sh[w * 2 + 1];
        }
        part[blockIdx.x] = make_double2(ts, tss);
    }
}

__global__ __launch_bounds__(256)
void stats_final_kernel(const double2* __restrict__ part, int nparts,
                        float2* __restrict__ stats, long long n) {
    double s = 0.0, ss = 0.0;
    for (int i = threadIdx.x; i < nparts; i += blockDim.x) {
        double2 p = part[i];
        s += p.x; ss += p.y;
    }
    for (int off = 32; off > 0; off >>= 1) {
        s  += __shfl_down(s,  off, 64);
        ss += __shfl_down(ss, off, 64);
    }
    __shared__ double sh[8];
    const int wave = threadIdx.x >> 6;
    if ((threadIdx.x & 63) == 0) { sh[wave * 2] = s; sh[wave * 2 + 1] = ss; }
    __syncthreads();
    if (threadIdx.x == 0) {
        double ts = 0.0, tss = 0.0;
        for (int w = 0; w < 4; ++w) { ts += sh[w * 2]; tss += sh[w * 2 + 1]; }
        double mu  = ts / (double)n;
        double var = tss / (double)n - mu * mu;
        float  sdf = (float)sqrt(fmax(var, 0.0));
        stats->x = (float)mu;
        stats->y = 3.0f * sdf;   // K_OUTLIER * sd, in fp32 like the reference
    }
}

// One 256-thread block handles exactly one quant block of 1024 elements
// (float4 per thread), so scale[blockIdx.x] is wave-uniform.
__global__ __launch_bounds__(256)
void quant_kernel(const float4* __restrict__ x4,
                  const float*  __restrict__ scale,
                  const float4* __restrict__ a4,
                  const int*    __restrict__ zp_ptr,
                  const float2* __restrict__ stats,
                  float4* __restrict__ out4) {
    const int i  = blockIdx.x * 256 + threadIdx.x;
    const float s   = scale[blockIdx.x];
    const float inv_s = 1.0f / s;   // note: reference divides; see below
    (void)inv_s;
    const float zp  = (float)(*zp_ptr);
    const float2 st = *stats;
    const float mu  = st.x;
    const float thr = st.y;

    float4 x = x4[i];
    float4 a = a4[i];
    float4 o;

    #pragma unroll
    for (int c = 0; c < 4; ++c) {
        float xc = (&x.x)[c];
        float ac = (&a.x)[c];
        // rectified sigmoid: clip(1.2*sigmoid(a) - 0.1, 0, 1)
        float sig = 1.0f / (1.0f + __expf(-ac));
        float h   = fminf(fmaxf(1.2f * sig - 0.1f, 0.0f), 1.0f);
        // IEEE divide to match reference bit-for-bit on the floor() input
        float xq  = floorf(xc / s) + h + zp;
        xq        = fminf(fmaxf(xq, 0.0f), 255.0f);
        float xd  = (xq - zp) * s;
        (&o.x)[c] = (fabsf(xc - mu) > thr) ? xc : xd;
    }
    out4[i] = o;
}

extern "C" void kernel_launch(void* const* d_in, const int* in_sizes, int n_in,
                              void* d_out, int out_size, void* d_ws, size_t ws_size,
                              hipStream_t stream) {
    const float* X     = (const float*)d_in[0];
    const float* scale = (const float*)d_in[1];
    const float* alpha = (const float*)d_in[2];
    const int*   zp    = (const int*)d_in[3];
    float* out         = (float*)d_out;

    const int n  = in_sizes[0];          // 45088768
    const int n4 = n / 4;                // 11272192
    const int qblocks = n / 1024;        // 44032

    double2* part  = (double2*)d_ws;
    float2*  stats = (float2*)(part + RED_BLOCKS);

    stats_partial_kernel<<<RED_BLOCKS, RED_THREADS, 0, stream>>>(
        (const float4*)X, part, n4);
    stats_final_kernel<<<1, 256, 0, stream>>>(part, RED_BLOCKS, stats, (long long)n);
    quant_kernel<<<qblocks, 256, 0, stream>>>(
        (const float4*)X, scale, (const float4*)alpha, zp, stats,
        (float4*)out);
}

// Round 3
// 417.439 us; speedup vs baseline: 1.0196x; 1.0196x over previous
//
#include <hip/hip_runtime.h>
#include <math.h>

// ---------------------------------------------------------------------------
// AdaRound fake-quantize with global outlier mask.
//  Phase 1: partial (sum, sumsq) of X -> ws (double2[RED_BLOCKS])
//           (regular loads: deliberately warms L3 with X for phase 3)
//  Phase 2: fold partials -> float2{mu, 3*sd} at ws + RED_BLOCKS
//  Phase 3: elementwise fake quant + outlier passthrough
//           (alpha loads + out stores NONTEMPORAL so X stays L3-resident)
// ---------------------------------------------------------------------------

typedef float f32x4 __attribute__((ext_vector_type(4)));  // native vec: ok for nontemporal builtins

constexpr int RED_BLOCKS  = 2048;
constexpr int RED_THREADS = 256;

__global__ __launch_bounds__(RED_THREADS)
void stats_partial_kernel(const f32x4* __restrict__ x4,
                          double2* __restrict__ part, int n4) {
    double s = 0.0, ss = 0.0;
    const int stride = gridDim.x * blockDim.x;
    for (int i = blockIdx.x * blockDim.x + threadIdx.x; i < n4; i += stride) {
        f32x4 v = x4[i];
        double vx = v.x, vy = v.y, vz = v.z, vw = v.w;
        s  += (vx + vy) + (vz + vw);
        ss += (vx * vx + vy * vy) + (vz * vz + vw * vw);
    }
    for (int off = 32; off > 0; off >>= 1) {
        s  += __shfl_down(s,  off, 64);
        ss += __shfl_down(ss, off, 64);
    }
    __shared__ double sh[8];
    const int wave = threadIdx.x >> 6;
    if ((threadIdx.x & 63) == 0) { sh[wave * 2] = s; sh[wave * 2 + 1] = ss; }
    __syncthreads();
    if (threadIdx.x == 0) {
        double ts = 0.0, tss = 0.0;
        for (int w = 0; w < (RED_THREADS >> 6); ++w) {
            ts += sh[w * 2]; tss += sh[w * 2 + 1];
        }
        part[blockIdx.x] = make_double2(ts, tss);
    }
}

__global__ __launch_bounds__(256)
void stats_final_kernel(const double2* __restrict__ part, int nparts,
                        float2* __restrict__ stats, long long n) {
    double s = 0.0, ss = 0.0;
    for (int i = threadIdx.x; i < nparts; i += blockDim.x) {
        double2 p = part[i];
        s += p.x; ss += p.y;
    }
    for (int off = 32; off > 0; off >>= 1) {
        s  += __shfl_down(s,  off, 64);
        ss += __shfl_down(ss, off, 64);
    }
    __shared__ double sh[8];
    const int wave = threadIdx.x >> 6;
    if ((threadIdx.x & 63) == 0) { sh[wave * 2] = s; sh[wave * 2 + 1] = ss; }
    __syncthreads();
    if (threadIdx.x == 0) {
        double ts = 0.0, tss = 0.0;
        for (int w = 0; w < 4; ++w) { ts += sh[w * 2]; tss += sh[w * 2 + 1]; }
        double mu  = ts / (double)n;
        double var = tss / (double)n - mu * mu;
        float  sdf = (float)sqrt(fmax(var, 0.0));
        float2 st;
        st.x = (float)mu;
        st.y = 3.0f * sdf;   // K_OUTLIER * sd
        *stats = st;
    }
}

// One 256-thread block handles TWO quant blocks (2048 elements, 2 float4 per
// thread). scale is wave-uniform within each half.
__global__ __launch_bounds__(256)
void quant_kernel(const f32x4* __restrict__ x4,
                  const float* __restrict__ scale,
                  const f32x4* __restrict__ a4,
                  const int*   __restrict__ zp_ptr,
                  const float2* __restrict__ stats,
                  f32x4* __restrict__ out4) {
    const int t = threadIdx.x;
    const long long base = (long long)blockIdx.x * 512;  // float4 units
    const float s0 = scale[blockIdx.x * 2];
    const float s1 = scale[blockIdx.x * 2 + 1];
    const float r0 = 1.0f / s0;          // one IEEE div per 1024 elements
    const float r1 = 1.0f / s1;
    const float zp = (float)(*zp_ptr);
    const float2 st = *stats;
    const float mu  = st.x;
    const float thr = st.y;

    f32x4 x0 = x4[base + t];
    f32x4 x1 = x4[base + 256 + t];
    f32x4 a0 = __builtin_nontemporal_load(&a4[base + t]);
    f32x4 a1 = __builtin_nontemporal_load(&a4[base + 256 + t]);

    f32x4 o0, o1;
    #pragma unroll
    for (int c = 0; c < 4; ++c) {
        {
            float xc = x0[c], ac = a0[c];
            float sig = 1.0f / (1.0f + __expf(-ac));
            float h   = fminf(fmaxf(1.2f * sig - 0.1f, 0.0f), 1.0f);
            float xq  = floorf(xc * r0) + h + zp;
            xq        = fminf(fmaxf(xq, 0.0f), 255.0f);
            float xd  = (xq - zp) * s0;
            o0[c] = (fabsf(xc - mu) > thr) ? xc : xd;
        }
        {
            float xc = x1[c], ac = a1[c];
            float sig = 1.0f / (1.0f + __expf(-ac));
            float h   = fminf(fmaxf(1.2f * sig - 0.1f, 0.0f), 1.0f);
            float xq  = floorf(xc * r1) + h + zp;
            xq        = fminf(fmaxf(xq, 0.0f), 255.0f);
            float xd  = (xq - zp) * s1;
            o1[c] = (fabsf(xc - mu) > thr) ? xc : xd;
        }
    }
    __builtin_nontemporal_store(o0, &out4[base + t]);
    __builtin_nontemporal_store(o1, &out4[base + 256 + t]);
}

extern "C" void kernel_launch(void* const* d_in, const int* in_sizes, int n_in,
                              void* d_out, int out_size, void* d_ws, size_t ws_size,
                              hipStream_t stream) {
    const float* X     = (const float*)d_in[0];
    const float* scale = (const float*)d_in[1];
    const float* alpha = (const float*)d_in[2];
    const int*   zp    = (const int*)d_in[3];
    float* out         = (float*)d_out;

    const int n  = in_sizes[0];          // 45088768
    const int n4 = n / 4;
    const int qpairs = n / 2048;         // 22016 blocks, 2 quant-blocks each

    double2* part  = (double2*)d_ws;
    float2*  stats = (float2*)(part + RED_BLOCKS);

    stats_partial_kernel<<<RED_BLOCKS, RED_THREADS, 0, stream>>>(
        (const f32x4*)X, part, n4);
    stats_final_kernel<<<1, 256, 0, stream>>>(part, RED_BLOCKS, stats, (long long)n);
    quant_kernel<<<qpairs, 256, 0, stream>>>(
        (const f32x4*)X, scale, (const f32x4*)alpha, zp, stats,
        (f32x4*)out);
}